// Round 8
// baseline (1632.440 us; speedup 1.0000x reference)
//
#include <hip/hip_runtime.h>
#include <stdint.h>
#include <stddef.h>

// ---------------------------------------------------------------------------
// 3-layer LSTM (B=64,T=256,F=64,H=1024) + tanh projection, bf16 MFMA + fp32 acc.
//
// Pipelined: ONE persistent kernel, 256 WGs (192 real = 64/layer, 64 clock-
// burners), 258-tick chain. Base = round-7 (1557us rec, 6.0us tick).
// Round-8 change (single variable vs r7): FUSED dual-matmul stream.
//   r7 serialized {poll prev -> mm_pk(x)} then {poll own -> mm_pk(h)} --
//   2 dependent poll chains + 2 first-load LLC RTs per tick, though both
//   inputs become ready at the same instant in steady state. Now:
//   pollge2 (both flags in one loop, independent loads -> 1 RT) and
//   mm_pk2 (all 64 loads in one depth-24 counted-vmcnt pipeline,
//   A/B streams interleaved). Layer 0 keeps single-stream mm_pk.
// ---------------------------------------------------------------------------

#define B_ 64
#define T_ 256
#define F_ 64
#define H_ 1024
#define NG_ 4096          // 4*H
#define MR_ (B_*T_)       // 16384 rows, row index = t*64 + b

typedef __attribute__((ext_vector_type(8))) short short8;
typedef __attribute__((ext_vector_type(4))) short short4v;
typedef __attribute__((ext_vector_type(4))) float f32x4;
typedef __attribute__((ext_vector_type(4))) unsigned int u32x4;
typedef unsigned short ushort_t;
typedef unsigned long long ull;

__device__ __forceinline__ float bf2f(ushort_t u) {
  union { float f; unsigned int i; } v; v.i = ((unsigned int)u) << 16; return v.f;
}
__device__ __forceinline__ ushort_t f2bf(float f) {
  union { float f; unsigned int i; } v; v.f = f;
  unsigned int i = v.i;
  unsigned int r = (i + 0x7fffu + ((i >> 16) & 1u)) >> 16;  // RNE
  return (ushort_t)r;
}

__device__ __forceinline__ void gload_lds16(const void* g, void* l) {
  __builtin_amdgcn_global_load_lds(
      (const __attribute__((address_space(1))) void*)g,
      (__attribute__((address_space(3))) void*)l, 16, 0, 0);
}

__device__ __forceinline__ float fsig(float x)  { return 1.f / (1.f + __expf(-x)); }
__device__ __forceinline__ float ftanh(float x) { return 1.f - 2.f / (1.f + __expf(2.f * x)); }

// ---------------------------------------------------------------------------
#define NFLAG 192                 // per-WG flags: 3 layers x 64 WGs
#define DONE_SLOT (NFLAG * 16)    // one done flag for the burners
#define NSLOTI ((NFLAG + 1) * 16) // 16-int (64B) stride
__global__ void init_sync_kernel(int* p) {
  for (int i = threadIdx.x; i < NSLOTI; i += blockDim.x)
    __hip_atomic_store(&p[i], 0, __ATOMIC_RELAXED, __HIP_MEMORY_SCOPE_AGENT);
}

// ---------------------------------------------------------------------------
// prep: bf16 casts, hi/lo packing for layer-1 (X ~ N(0,1) needs >bf16), biases.
__global__ void prep_kernel(
    const float* __restrict__ X,
    const float* __restrict__ wih1, const float* __restrict__ whh1,
    const float* __restrict__ bih1, const float* __restrict__ bhh1,
    const float* __restrict__ wih2, const float* __restrict__ whh2,
    const float* __restrict__ bih2, const float* __restrict__ bhh2,
    const float* __restrict__ wih3, const float* __restrict__ whh3,
    const float* __restrict__ bih3, const float* __restrict__ bhh3,
    const float* __restrict__ wout,
    ushort_t* __restrict__ whh_bf, ushort_t* __restrict__ wih_bf,
    ushort_t* __restrict__ w1p, ushort_t* __restrict__ xp,
    ushort_t* __restrict__ wout_bf, float* __restrict__ bias)
{
  long long i0 = (long long)blockIdx.x * blockDim.x + threadIdx.x;
  long long stride = (long long)gridDim.x * blockDim.x;
  const long long NW = (long long)NG_ * H_;  // 4M

  for (long long i = i0; i < NW; i += stride) whh_bf[i]        = f2bf(whh1[i]);
  for (long long i = i0; i < NW; i += stride) whh_bf[NW + i]   = f2bf(whh2[i]);
  for (long long i = i0; i < NW; i += stride) whh_bf[2*NW + i] = f2bf(whh3[i]);
  for (long long i = i0; i < NW; i += stride) wih_bf[i]        = f2bf(wih2[i]);
  for (long long i = i0; i < NW; i += stride) wih_bf[NW + i]   = f2bf(wih3[i]);

  // W1 pack: row n of [4096][256] = [w_hi | w_hi | w_lo | w_lo]
  for (long long i = i0; i < (long long)NG_ * F_; i += stride) {
    int n = (int)(i / F_), f = (int)(i % F_);
    float wv = wih1[i];
    ushort_t hi = f2bf(wv);
    ushort_t lo = f2bf(wv - bf2f(hi));
    ushort_t* row = w1p + (long long)n * 256;
    row[f] = hi; row[64 + f] = hi; row[128 + f] = lo; row[192 + f] = lo;
  }
  // X pack: row (t*64+b) of [16384][256] = [x_hi | x_lo | x_hi | x_lo]
  for (long long i = i0; i < (long long)MR_ * F_; i += stride) {
    int b = (int)(i / (T_ * F_));
    int rem = (int)(i % (T_ * F_));
    int t = rem / F_, f = rem % F_;
    float xv = X[i];
    ushort_t hi = f2bf(xv);
    ushort_t lo = f2bf(xv - bf2f(hi));
    ushort_t* row = xp + ((long long)(t * B_ + b)) * 256;
    row[f] = hi; row[64 + f] = lo; row[128 + f] = hi; row[192 + f] = lo;
  }
  for (long long i = i0; i < (long long)F_ * H_; i += stride) wout_bf[i] = f2bf(wout[i]);
  for (long long i = i0; i < NG_; i += stride) {
    bias[i]          = bih1[i] + bhh1[i];
    bias[NG_ + i]    = bih2[i] + bhh2[i];
    bias[2*NG_ + i]  = bih3[i] + bhh3[i];
  }
}

// ---------------------------------------------------------------------------
// Packed-seq element offset for (row m in [0,16384), k in [0,1024)):
// seq[t = m>>6][wg = k>>4][b = m&63][jl = k&15]
__device__ __forceinline__ size_t pk_off(int row, int k) {
  return ((size_t)((row >> 6) * 64 + (k >> 4)) * 64 + (row & 63)) * 16 + (k & 15);
}

// ---------------------------------------------------------------------------
// GEMM (final projection): C[M=16384, n<64] = A[M,K=1024] * B[n,K]^T, tanh
// epilogue, scatter to [b][t][f] fp32. A is in PACKED seq layout.
__global__ __launch_bounds__(256) void gemm_kernel(
    const ushort_t* __restrict__ A, const ushort_t* __restrict__ Bm,
    const float* __restrict__ bias, void* __restrict__ out,
    int K, int Nreal)
{
  __shared__ ushort_t As[128 * 64];
  __shared__ ushort_t Bs[128 * 64];
  const int tid = threadIdx.x;
  const int w = tid >> 6, lane = tid & 63;
  const int mq = w & 1, nq = w >> 1;
  const int m0 = blockIdx.x * 128, n0 = blockIdx.y * 128;
  const int l8 = lane >> 3, l7 = lane & 7;
  const int kp = l7 ^ l8;  // fetch swizzle so LDS[r][p] holds kpart p^(r&7)

  f32x4 acc[4][4] = {};

  for (int k0 = 0; k0 < K; k0 += 64) {
    #pragma unroll
    for (int q = 0; q < 4; q++) {
      int c = w * 4 + q;                   // chunk 0..15, rows c*8..c*8+7
      int rowA = m0 + c * 8 + l8;
      gload_lds16(A + pk_off(rowA, k0 + kp * 8), (char*)As + c * 1024);
      int rowB = n0 + c * 8 + l8;
      if (rowB >= Nreal) rowB = Nreal - 1;
      gload_lds16(Bm + (size_t)rowB * K + k0 + kp * 8, (char*)Bs + c * 1024);
    }
    __syncthreads();
    #pragma unroll
    for (int ks = 0; ks < 2; ks++) {
      short8 af[4], bf[4];
      #pragma unroll
      for (int mt = 0; mt < 4; mt++) {
        int r = mq * 64 + mt * 16 + (lane & 15);
        int pos = (ks * 4 + (lane >> 4)) ^ (r & 7);
        af[mt] = *(const short8*)((const char*)As + r * 128 + pos * 16);
      }
      #pragma unroll
      for (int nt = 0; nt < 4; nt++) {
        int r = nq * 64 + nt * 16 + (lane & 15);
        int pos = (ks * 4 + (lane >> 4)) ^ (r & 7);
        bf[nt] = *(const short8*)((const char*)Bs + r * 128 + pos * 16);
      }
      #pragma unroll
      for (int mt = 0; mt < 4; mt++)
        #pragma unroll
        for (int nt = 0; nt < 4; nt++)
          acc[mt][nt] = __builtin_amdgcn_mfma_f32_16x16x32_bf16(
              af[mt], bf[nt], acc[mt][nt], 0, 0, 0);
    }
    __syncthreads();
  }

  #pragma unroll
  for (int mt = 0; mt < 4; mt++) {
    #pragma unroll
    for (int nt = 0; nt < 4; nt++) {
      #pragma unroll
      for (int r = 0; r < 4; r++) {
        int m = m0 + mq * 64 + mt * 16 + (lane >> 4) * 4 + r;
        int n = n0 + nq * 64 + nt * 16 + (lane & 15);
        float v = acc[mt][nt][r];
        if (n < Nreal) {
          v = tanhf(v + bias[n]);
          int t = m >> 6, b = m & 63;           // m = t*64 + b
          ((float*)out)[((size_t)(b * T_ + t)) * F_ + n] = v;
        }
      }
    }
  }
}

// ---------------------------------------------------------------------------
// Pipelined sc1 h-load engine. Frag (mt,ks) lives at lane-base + ks*2048 +
// mt*256 elements (contiguous 16B). Groups of 8 frags (ks pair x mt 0..3).
__device__ __forceinline__ void issue8(const ushort_t* lb, int ks0, u32x4* f) {
  #pragma unroll
  for (int j = 0; j < 8; j++) {
    int mt = j & 3, ks = ks0 + (j >> 2);
    asm volatile("global_load_dwordx4 %0, %1, off sc1"
                 : "=&v"(f[j])
                 : "v"(lb + (size_t)ks * 2048 + mt * 256)
                 : "memory");
  }
}
// counted waits; carry group regs as inout so consumers have a true data
// dependency on the wait (no MFMA hoisting past it).
__device__ __forceinline__ void wait16(u32x4* f) {
  asm volatile("s_waitcnt vmcnt(16)"
               : "+v"(f[0]), "+v"(f[1]), "+v"(f[2]), "+v"(f[3]),
                 "+v"(f[4]), "+v"(f[5]), "+v"(f[6]), "+v"(f[7])
               :: "memory");
}
__device__ __forceinline__ void wait8(u32x4* f) {
  asm volatile("s_waitcnt vmcnt(8)"
               : "+v"(f[0]), "+v"(f[1]), "+v"(f[2]), "+v"(f[3]),
                 "+v"(f[4]), "+v"(f[5]), "+v"(f[6]), "+v"(f[7])
               :: "memory");
}
__device__ __forceinline__ void wait0(u32x4* f) {
  asm volatile("s_waitcnt vmcnt(0)"
               : "+v"(f[0]), "+v"(f[1]), "+v"(f[2]), "+v"(f[3]),
                 "+v"(f[4]), "+v"(f[5]), "+v"(f[6]), "+v"(f[7])
               :: "memory");
}
__device__ __forceinline__ void mfma8(const u32x4* f, int ks0,
    const short8 (&bfr)[4][8], f32x4 (&acc)[4][4]) {
  #pragma unroll
  for (int j = 0; j < 8; j++) {
    int mt = j & 3, ks = ks0 + (j >> 2);
    union { u32x4 u; short8 s; } a; a.u = f[j];
    #pragma unroll
    for (int nt = 0; nt < 4; nt++)
      acc[mt][nt] = __builtin_amdgcn_mfma_f32_16x16x32_bf16(
          a.s, bfr[nt][ks], acc[mt][nt], 0, 0, 0);
  }
}

// Single-stream matmul (layer 0 h-phase): depth-2 ping-pong (r7, proven).
__device__ __forceinline__ void mm_pk(
    const ushort_t* base, int kq, int l15, int l4,
    const short8 (&bfr)[4][8], f32x4 (&acc)[4][4])
{
  const ushort_t* lb = base +
      ((size_t)(kq * 16 + (l4 >> 1)) * 64 + l15) * 16 + (l4 & 1) * 8;
  u32x4 f0[8], f1[8], f2[8], f3[8];
  issue8(lb, 0, f0);
  issue8(lb, 2, f1);
  wait8(f0); mfma8(f0, 0, bfr, acc);
  issue8(lb, 4, f2);
  wait8(f1); mfma8(f1, 2, bfr, acc);
  issue8(lb, 6, f3);
  wait8(f2); mfma8(f2, 4, bfr, acc);
  wait0(f3); mfma8(f3, 6, bfr, acc);
}

// ROUND 8: fused dual-stream matmul (layers 1,2). Both input tiles ready at
// entry; 64 loads flow through one depth-24 pipeline, A/B interleaved so B's
// first loads issue during A's MFMAs. One first-RT instead of two.
__device__ __forceinline__ void mm_pk2(
    const ushort_t* baseA, const short8 (&bfrA)[4][8],
    const ushort_t* baseB, const short8 (&bfrB)[4][8],
    int kq, int l15, int l4, f32x4 (&acc)[4][4])
{
  const size_t lo =
      ((size_t)(kq * 16 + (l4 >> 1)) * 64 + l15) * 16 + (l4 & 1) * 8;
  const ushort_t* la = baseA + lo;
  const ushort_t* lb = baseB + lo;
  u32x4 a0[8], a1[8], a2[8], a3[8], b0[8], b1[8], b2[8], b3[8];
  issue8(la, 0, a0); issue8(la, 2, a1); issue8(lb, 0, b0);   // 24 in flight
  wait16(a0); mfma8(a0, 0, bfrA, acc); issue8(lb, 2, b1);
  wait16(a1); mfma8(a1, 2, bfrA, acc); issue8(la, 4, a2);
  wait16(b0); mfma8(b0, 0, bfrB, acc); issue8(la, 6, a3);
  wait16(b1); mfma8(b1, 2, bfrB, acc); issue8(lb, 4, b2);
  wait16(a2); mfma8(a2, 4, bfrA, acc); issue8(lb, 6, b3);
  wait16(a3); mfma8(a3, 6, bfrA, acc);
  wait8(b2);  mfma8(b2, 4, bfrB, acc);
  wait0(b3);  mfma8(b3, 6, bfrB, acc);
}

// ---------------------------------------------------------------------------
// ballot-polls: lanes 0..15 watch the 16 producer WGs of this wave's K-slice
// (lanes 16-63 mirror). Flags stay sc1 atomics.
__device__ __forceinline__ void pollge(const int* p, int tgt) {
  int v = __hip_atomic_load(p, __ATOMIC_RELAXED, __HIP_MEMORY_SCOPE_AGENT);
  while (__ballot(v >= tgt) != ~0ull) {
    __builtin_amdgcn_s_sleep(1);
    v = __hip_atomic_load(p, __ATOMIC_RELAXED, __HIP_MEMORY_SCOPE_AGENT);
  }
}
// combined poll: both flags checked per iteration (independent loads -> the
// two LLC accesses overlap instead of chaining).
__device__ __forceinline__ void pollge2(const int* p1, int t1,
                                        const int* p2, int t2) {
  int v1 = __hip_atomic_load(p1, __ATOMIC_RELAXED, __HIP_MEMORY_SCOPE_AGENT);
  int v2 = __hip_atomic_load(p2, __ATOMIC_RELAXED, __HIP_MEMORY_SCOPE_AGENT);
  while (__ballot((v1 >= t1) && (v2 >= t2)) != ~0ull) {
    __builtin_amdgcn_s_sleep(1);
    v1 = __hip_atomic_load(p1, __ATOMIC_RELAXED, __HIP_MEMORY_SCOPE_AGENT);
    v2 = __hip_atomic_load(p2, __ATOMIC_RELAXED, __HIP_MEMORY_SCOPE_AGENT);
  }
}

// ---------------------------------------------------------------------------
// Pipelined recurrence: blocks 0..191 real (layer = b/64, wg = b%64),
// blocks 192..255 clock-burners. 4 waves = 4-way K-split.
__global__ __launch_bounds__(256, 1) void rec_pipe_kernel(
    const ushort_t* __restrict__ xp, const ushort_t* __restrict__ w1p,
    const ushort_t* __restrict__ whh, const ushort_t* __restrict__ wih23,
    const float* __restrict__ bias,
    ushort_t* __restrict__ seq1, ushort_t* __restrict__ seq2,
    ushort_t* __restrict__ seq3, int* __restrict__ slots)
{
  __shared__ float PG[4][64][68];      // 4 disjoint K-partial buffers (69.6KB)
  __shared__ float lds_pad[4096];      // +16KB -> 86KB: force 1 WG/CU

  if (blockIdx.x >= 192) {
    // ---- clock burner: register-only MFMA until done-flag ----
    if (threadIdx.x == 0) lds_pad[0] = 0.f;   // keep pad allocated
    __syncthreads();
    short8 a;
    #pragma unroll
    for (int i = 0; i < 8; i++) a[i] = (short)(threadIdx.x + i);
    f32x4 d0 = {}, d1 = {}, d2 = {}, d3 = {};
    const int* done = slots + DONE_SLOT;
    for (;;) {
      #pragma unroll
      for (int i = 0; i < 32; i++) {
        d0 = __builtin_amdgcn_mfma_f32_16x16x32_bf16(a, a, d0, 0, 0, 0);
        d1 = __builtin_amdgcn_mfma_f32_16x16x32_bf16(a, a, d1, 0, 0, 0);
        d2 = __builtin_amdgcn_mfma_f32_16x16x32_bf16(a, a, d2, 0, 0, 0);
        d3 = __builtin_amdgcn_mfma_f32_16x16x32_bf16(a, a, d3, 0, 0, 0);
      }
      asm volatile("" :: "v"(d0[0]), "v"(d1[0]), "v"(d2[0]), "v"(d3[0]));
      if (__hip_atomic_load(done, __ATOMIC_RELAXED, __HIP_MEMORY_SCOPE_AGENT))
        return;
    }
  }

  const int layer = blockIdx.x >> 6;   // 0..2
  const int wg = blockIdx.x & 63;      // 0..63
  const int tid = threadIdx.x;
  const int kq = tid >> 6, lane = tid & 63;
  const int l15 = lane & 15, l4 = lane >> 4;
  const int jWG = wg * 16;

  ushort_t* my_seq   = (layer == 0) ? seq1 : (layer == 1) ? seq2 : seq3;
  const ushort_t* pv_seq = (layer == 1) ? seq1 : seq2;   // used when layer>0

  // persistent W_hh fragments: (nt=gate, ks): n = nt*1024+jWG+l15,
  // k = kq*256 + ks*32 + l4*8.  128 VGPRs.
  short8 bhh[4][8];
  {
    const ushort_t* wl = whh + (size_t)layer * NG_ * H_;
    #pragma unroll
    for (int nt = 0; nt < 4; nt++)
      #pragma unroll
      for (int ks = 0; ks < 8; ks++)
        bhh[nt][ks] = *(const short8*)(
            wl + ((size_t)(nt * H_ + jWG + l15)) * H_ + kq * 256 + ks * 32 + l4 * 8);
  }
  // W_ih fragments. Layer 0: K=256 total -> wave kq covers k = kq*64 + ks*32,
  // ks in 0..1 (slots [*][0..1]). Layers 1,2: full 8 slots, K layout as bhh.
  short8 bih[4][8];
  if (layer == 0) {
    #pragma unroll
    for (int nt = 0; nt < 4; nt++)
      #pragma unroll
      for (int ks = 0; ks < 2; ks++)
        bih[nt][ks] = *(const short8*)(
            w1p + ((size_t)(nt * H_ + jWG + l15)) * 256 + kq * 64 + ks * 32 + l4 * 8);
  } else {
    const ushort_t* wl = wih23 + (size_t)(layer - 1) * NG_ * H_;
    #pragma unroll
    for (int nt = 0; nt < 4; nt++)
      #pragma unroll
      for (int ks = 0; ks < 8; ks++)
        bih[nt][ks] = *(const short8*)(
            wl + ((size_t)(nt * H_ + jWG + l15)) * H_ + kq * 256 + ks * 32 + l4 * 8);
  }

  // elementwise ownership (round-5 remap, kept): thread (kq,lane) owns
  // batch row eb = kq*16+(lane>>2), j-quad ejq = lane&3.
  const int eb  = kq * 16 + (lane >> 2);
  const int ejq = lane & 3;
  float cst[4] = {0.f, 0.f, 0.f, 0.f};

  // bias enters through xv (constant across t) for ALL layers.
  f32x4 xv[4];
  #pragma unroll
  for (int g = 0; g < 4; g++)
    xv[g] = *(const f32x4*)&bias[layer * NG_ + g * H_ + jWG + ejq * 4];

  const int* slot_own  = slots + (layer * 64 + kq * 16 + l15) * 16;
  const int* slot_prev = slots + ((layer - (layer > 0)) * 64 + kq * 16 + l15) * 16;
  int* slot_my = slots + (layer * 64 + wg) * 16;

  for (int t = 0; t < T_; t++) {
    f32x4 acc[4][4] = {};

    if (layer == 0) {
      // x A-frags: plain cached loads, no flag dependency -> issue pre-poll.
      short8 ax[4][2];
      #pragma unroll
      for (int mt = 0; mt < 4; mt++)
        #pragma unroll
        for (int ks = 0; ks < 2; ks++)
          ax[mt][ks] = *(const short8*)(
              xp + ((size_t)(t * B_ + mt * 16 + l15)) * 256 + kq * 64 + ks * 32 + l4 * 8);
      #pragma unroll
      for (int ks = 0; ks < 2; ks++)
        #pragma unroll
        for (int mt = 0; mt < 4; mt++)
          #pragma unroll
          for (int nt = 0; nt < 4; nt++)
            acc[mt][nt] = __builtin_amdgcn_mfma_f32_16x16x32_bf16(
                ax[mt][ks], bih[nt][ks], acc[mt][nt], 0, 0, 0);
      if (t > 0) {
        pollge(slot_own, t);               // own layer finished step t-1
        __builtin_amdgcn_sched_barrier(0);
        mm_pk(my_seq + (size_t)(t - 1) * 65536, kq, l15, l4, bhh, acc);
      }
    } else {
      if (t > 0) {
        // both inputs become ready at the same instant: one combined poll,
        // one fused load/MFMA stream.
        pollge2(slot_prev, t + 1, slot_own, t);
        __builtin_amdgcn_sched_barrier(0);
        mm_pk2(pv_seq + (size_t)t * 65536, bih,
               my_seq + (size_t)(t - 1) * 65536, bhh,
               kq, l15, l4, acc);
      } else {
        pollge(slot_prev, 1);
        __builtin_amdgcn_sched_barrier(0);
        mm_pk(pv_seq, kq, l15, l4, bih, acc);
      }
    }

    // ---- K-partial reduction: 4 disjoint LDS buffers, no atomics ----
    #pragma unroll
    for (int mt = 0; mt < 4; mt++)
      #pragma unroll
      for (int nt = 0; nt < 4; nt++)
        #pragma unroll
        for (int r = 0; r < 4; r++)
          PG[kq][mt * 16 + l4 * 4 + r][nt * 16 + l15] = acc[mt][nt][r];
    __syncthreads();

    // elementwise LSTM cell: thread owns (eb, j = jWG + ejq*4 + u)
    f32x4 p[4];
    #pragma unroll
    for (int g = 0; g < 4; g++) {
      f32x4 p0 = *(const f32x4*)&PG[0][eb][g * 16 + ejq * 4];
      f32x4 p1 = *(const f32x4*)&PG[1][eb][g * 16 + ejq * 4];
      f32x4 p2 = *(const f32x4*)&PG[2][eb][g * 16 + ejq * 4];
      f32x4 p3 = *(const f32x4*)&PG[3][eb][g * 16 + ejq * 4];
      p[g] = (p0 + p1) + (p2 + p3) + xv[g];
    }
    short4v hb;
    #pragma unroll
    for (int u = 0; u < 4; u++) {
      float ii = fsig(p[0][u]);
      float ff = fsig(p[1][u]);
      float gg = ftanh(p[2][u]);
      float oo = fsig(p[3][u]);
      cst[u] = ff * cst[u] + ii * gg;
      hb[u] = (short)f2bf(oo * ftanh(cst[u]));
    }
    union { short4v s; ull u; } hh; hh.s = hb;
    // PACKED store: seq[t][wg][eb][ejq*4..+3]; per wave one contiguous 512B
    // block (tile + kq*512 + lane*8) -> full-line writes, sc1 (bypass L2).
    __hip_atomic_store(
        (ull*)(my_seq + (size_t)t * 65536 + (size_t)wg * 1024
               + (size_t)eb * 16 + ejq * 4),
        hh.u, __ATOMIC_RELAXED, __HIP_MEMORY_SCOPE_AGENT);

    // publish: drain own stores, WG-join (doubles as PG read-complete
    // barrier), then one flag store per WG.
    __builtin_amdgcn_s_waitcnt(0);
    __syncthreads();
    if (tid == 0)
      __hip_atomic_store(slot_my, t + 1,
                         __ATOMIC_RELAXED, __HIP_MEMORY_SCOPE_AGENT);
  }

  // layer-2 WGs release the burners
  if (layer == 2 && tid == 0)
    __hip_atomic_store(slots + DONE_SLOT, 1,
                       __ATOMIC_RELAXED, __HIP_MEMORY_SCOPE_AGENT);
}

// ---------------------------------------------------------------------------
extern "C" void kernel_launch(void* const* d_in, const int* in_sizes, int n_in,
                              void* d_out, int out_size, void* d_ws, size_t ws_size,
                              hipStream_t stream)
{
  (void)in_sizes; (void)n_in; (void)out_size; (void)ws_size;
  const float* X    = (const float*)d_in[0];
  const float* wih1 = (const float*)d_in[1];
  const float* whh1 = (const float*)d_in[2];
  const float* bih1 = (const float*)d_in[3];
  const float* bhh1 = (const float*)d_in[4];
  const float* wih2 = (const float*)d_in[5];
  const float* whh2 = (const float*)d_in[6];
  const float* bih2 = (const float*)d_in[7];
  const float* bhh2 = (const float*)d_in[8];
  const float* wih3 = (const float*)d_in[9];
  const float* whh3 = (const float*)d_in[10];
  const float* bih3 = (const float*)d_in[11];
  const float* bhh3 = (const float*)d_in[12];
  const float* wout = (const float*)d_in[13];
  const float* bout = (const float*)d_in[14];

  const size_t NW = (size_t)NG_ * H_;           // 4M elems
  const size_t sz_seq  = (size_t)MR_ * H_ * 2;  // bf16 h sequence, per layer
  const size_t sz_whh  = 3 * NW * 2;
  const size_t sz_wih  = 2 * NW * 2;
  const size_t sz_w1p  = (size_t)NG_ * 256 * 2;
  const size_t sz_xp   = (size_t)MR_ * 256 * 2;
  const size_t sz_wout = (size_t)F_ * H_ * 2;
  const size_t sz_bias = 3 * (size_t)NG_ * 4;
  const size_t sz_slot = NSLOTI * 4;

  char* ws = (char*)d_ws;
  size_t off = 0;
  auto alloc = [&](size_t bytes) -> void* {
    void* p = ws + off; off += (bytes + 255) & ~(size_t)255; return p;
  };
  ushort_t* seq1    = (ushort_t*)alloc(sz_seq);
  ushort_t* seq2    = (ushort_t*)alloc(sz_seq);
  ushort_t* seq3    = (ushort_t*)alloc(sz_seq);
  ushort_t* whh_bf  = (ushort_t*)alloc(sz_whh);
  ushort_t* wih_bf  = (ushort_t*)alloc(sz_wih);
  ushort_t* w1p     = (ushort_t*)alloc(sz_w1p);
  ushort_t* xp      = (ushort_t*)alloc(sz_xp);
  ushort_t* wout_bf = (ushort_t*)alloc(sz_wout);
  float*    bias    = (float*)alloc(sz_bias);
  int*      slots   = (int*)alloc(sz_slot);
  // total ~146 MB

  init_sync_kernel<<<1, 256, 0, stream>>>(slots);
  prep_kernel<<<1024, 256, 0, stream>>>(
      X, wih1, whh1, bih1, bhh1, wih2, whh2, bih2, bhh2,
      wih3, whh3, bih3, bhh3, wout,
      whh_bf, wih_bf, w1p, xp, wout_bf, bias);

  rec_pipe_kernel<<<256, 256, 0, stream>>>(
      xp, w1p, whh_bf, wih_bf, bias, seq1, seq2, seq3, slots);

  gemm_kernel<<<dim3(128, 1), dim3(256), 0, stream>>>(
      seq3, wout_bf, bout, d_out, 1024, F_);
}

// Round 9
// 1614.692 us; speedup vs baseline: 1.0110x; 1.0110x over previous
//
#include <hip/hip_runtime.h>
#include <stdint.h>
#include <stddef.h>

// ---------------------------------------------------------------------------
// 3-layer LSTM (B=64,T=256,F=64,H=1024) + tanh projection, bf16 MFMA + fp32 acc.
//
// Pipelined: ONE persistent kernel, 256 WGs (192 real = 64/layer, 64 clock-
// burners), 258-tick chain. Base = round-7 (1557us rec, 6.0us tick, 216 VGPR).
// Round-9 change (single variable vs r7): h-loads WITHOUT sc1 (L2-cacheable).
//   r8 (fused streams) was neutral -> the residual is the streaming load
//   phase itself. With sc1, all 64 consumer WGs/layer re-read the same 128KB
//   tile from LLC every tick (~40MB/tick, ~2.7us at LLC BW) with ~700cy
//   latency per wait group. Without sc1, the 16 synchronized WGs per XCD
//   merge in L2 MSHRs (one LLC fill per line per XCD, 16-way broadcast):
//   ~8x LLC-traffic cut + L2-hit latency for late requesters. r6's plain-
//   load regression was compiler scheduling (no hand pipeline), not the L2
//   path -- this is the clean A/B with the r7 asm engine held fixed.
//   Safety: every seq address is written once per dispatch via sc1 store
//   (LLC authoritative; no L2 can hold a fresher copy) and read only after
//   the flag -> any L2 fill is post-publish, hence fresh. gemm_kernel has
//   always read sc1-written seq3 via plain loads and passes.
// ---------------------------------------------------------------------------

#define B_ 64
#define T_ 256
#define F_ 64
#define H_ 1024
#define NG_ 4096          // 4*H
#define MR_ (B_*T_)       // 16384 rows, row index = t*64 + b

typedef __attribute__((ext_vector_type(8))) short short8;
typedef __attribute__((ext_vector_type(4))) short short4v;
typedef __attribute__((ext_vector_type(4))) float f32x4;
typedef __attribute__((ext_vector_type(4))) unsigned int u32x4;
typedef unsigned short ushort_t;
typedef unsigned long long ull;

__device__ __forceinline__ float bf2f(ushort_t u) {
  union { float f; unsigned int i; } v; v.i = ((unsigned int)u) << 16; return v.f;
}
__device__ __forceinline__ ushort_t f2bf(float f) {
  union { float f; unsigned int i; } v; v.f = f;
  unsigned int i = v.i;
  unsigned int r = (i + 0x7fffu + ((i >> 16) & 1u)) >> 16;  // RNE
  return (ushort_t)r;
}

__device__ __forceinline__ void gload_lds16(const void* g, void* l) {
  __builtin_amdgcn_global_load_lds(
      (const __attribute__((address_space(1))) void*)g,
      (__attribute__((address_space(3))) void*)l, 16, 0, 0);
}

__device__ __forceinline__ float fsig(float x)  { return 1.f / (1.f + __expf(-x)); }
__device__ __forceinline__ float ftanh(float x) { return 1.f - 2.f / (1.f + __expf(2.f * x)); }

// ---------------------------------------------------------------------------
#define NFLAG 192                 // per-WG flags: 3 layers x 64 WGs
#define DONE_SLOT (NFLAG * 16)    // one done flag for the burners
#define NSLOTI ((NFLAG + 1) * 16) // 16-int (64B) stride
__global__ void init_sync_kernel(int* p) {
  for (int i = threadIdx.x; i < NSLOTI; i += blockDim.x)
    __hip_atomic_store(&p[i], 0, __ATOMIC_RELAXED, __HIP_MEMORY_SCOPE_AGENT);
}

// ---------------------------------------------------------------------------
// prep: bf16 casts, hi/lo packing for layer-1 (X ~ N(0,1) needs >bf16), biases.
__global__ void prep_kernel(
    const float* __restrict__ X,
    const float* __restrict__ wih1, const float* __restrict__ whh1,
    const float* __restrict__ bih1, const float* __restrict__ bhh1,
    const float* __restrict__ wih2, const float* __restrict__ whh2,
    const float* __restrict__ bih2, const float* __restrict__ bhh2,
    const float* __restrict__ wih3, const float* __restrict__ whh3,
    const float* __restrict__ bih3, const float* __restrict__ bhh3,
    const float* __restrict__ wout,
    ushort_t* __restrict__ whh_bf, ushort_t* __restrict__ wih_bf,
    ushort_t* __restrict__ w1p, ushort_t* __restrict__ xp,
    ushort_t* __restrict__ wout_bf, float* __restrict__ bias)
{
  long long i0 = (long long)blockIdx.x * blockDim.x + threadIdx.x;
  long long stride = (long long)gridDim.x * blockDim.x;
  const long long NW = (long long)NG_ * H_;  // 4M

  for (long long i = i0; i < NW; i += stride) whh_bf[i]        = f2bf(whh1[i]);
  for (long long i = i0; i < NW; i += stride) whh_bf[NW + i]   = f2bf(whh2[i]);
  for (long long i = i0; i < NW; i += stride) whh_bf[2*NW + i] = f2bf(whh3[i]);
  for (long long i = i0; i < NW; i += stride) wih_bf[i]        = f2bf(wih2[i]);
  for (long long i = i0; i < NW; i += stride) wih_bf[NW + i]   = f2bf(wih3[i]);

  // W1 pack: row n of [4096][256] = [w_hi | w_hi | w_lo | w_lo]
  for (long long i = i0; i < (long long)NG_ * F_; i += stride) {
    int n = (int)(i / F_), f = (int)(i % F_);
    float wv = wih1[i];
    ushort_t hi = f2bf(wv);
    ushort_t lo = f2bf(wv - bf2f(hi));
    ushort_t* row = w1p + (long long)n * 256;
    row[f] = hi; row[64 + f] = hi; row[128 + f] = lo; row[192 + f] = lo;
  }
  // X pack: row (t*64+b) of [16384][256] = [x_hi | x_lo | x_hi | x_lo]
  for (long long i = i0; i < (long long)MR_ * F_; i += stride) {
    int b = (int)(i / (T_ * F_));
    int rem = (int)(i % (T_ * F_));
    int t = rem / F_, f = rem % F_;
    float xv = X[i];
    ushort_t hi = f2bf(xv);
    ushort_t lo = f2bf(xv - bf2f(hi));
    ushort_t* row = xp + ((long long)(t * B_ + b)) * 256;
    row[f] = hi; row[64 + f] = lo; row[128 + f] = hi; row[192 + f] = lo;
  }
  for (long long i = i0; i < (long long)F_ * H_; i += stride) wout_bf[i] = f2bf(wout[i]);
  for (long long i = i0; i < NG_; i += stride) {
    bias[i]          = bih1[i] + bhh1[i];
    bias[NG_ + i]    = bih2[i] + bhh2[i];
    bias[2*NG_ + i]  = bih3[i] + bhh3[i];
  }
}

// ---------------------------------------------------------------------------
// Packed-seq element offset for (row m in [0,16384), k in [0,1024)):
// seq[t = m>>6][wg = k>>4][b = m&63][jl = k&15]
__device__ __forceinline__ size_t pk_off(int row, int k) {
  return ((size_t)((row >> 6) * 64 + (k >> 4)) * 64 + (row & 63)) * 16 + (k & 15);
}

// ---------------------------------------------------------------------------
// GEMM (final projection): C[M=16384, n<64] = A[M,K=1024] * B[n,K]^T, tanh
// epilogue, scatter to [b][t][f] fp32. A is in PACKED seq layout.
__global__ __launch_bounds__(256) void gemm_kernel(
    const ushort_t* __restrict__ A, const ushort_t* __restrict__ Bm,
    const float* __restrict__ bias, void* __restrict__ out,
    int K, int Nreal)
{
  __shared__ ushort_t As[128 * 64];
  __shared__ ushort_t Bs[128 * 64];
  const int tid = threadIdx.x;
  const int w = tid >> 6, lane = tid & 63;
  const int mq = w & 1, nq = w >> 1;
  const int m0 = blockIdx.x * 128, n0 = blockIdx.y * 128;
  const int l8 = lane >> 3, l7 = lane & 7;
  const int kp = l7 ^ l8;  // fetch swizzle so LDS[r][p] holds kpart p^(r&7)

  f32x4 acc[4][4] = {};

  for (int k0 = 0; k0 < K; k0 += 64) {
    #pragma unroll
    for (int q = 0; q < 4; q++) {
      int c = w * 4 + q;                   // chunk 0..15, rows c*8..c*8+7
      int rowA = m0 + c * 8 + l8;
      gload_lds16(A + pk_off(rowA, k0 + kp * 8), (char*)As + c * 1024);
      int rowB = n0 + c * 8 + l8;
      if (rowB >= Nreal) rowB = Nreal - 1;
      gload_lds16(Bm + (size_t)rowB * K + k0 + kp * 8, (char*)Bs + c * 1024);
    }
    __syncthreads();
    #pragma unroll
    for (int ks = 0; ks < 2; ks++) {
      short8 af[4], bf[4];
      #pragma unroll
      for (int mt = 0; mt < 4; mt++) {
        int r = mq * 64 + mt * 16 + (lane & 15);
        int pos = (ks * 4 + (lane >> 4)) ^ (r & 7);
        af[mt] = *(const short8*)((const char*)As + r * 128 + pos * 16);
      }
      #pragma unroll
      for (int nt = 0; nt < 4; nt++) {
        int r = nq * 64 + nt * 16 + (lane & 15);
        int pos = (ks * 4 + (lane >> 4)) ^ (r & 7);
        bf[nt] = *(const short8*)((const char*)Bs + r * 128 + pos * 16);
      }
      #pragma unroll
      for (int mt = 0; mt < 4; mt++)
        #pragma unroll
        for (int nt = 0; nt < 4; nt++)
          acc[mt][nt] = __builtin_amdgcn_mfma_f32_16x16x32_bf16(
              af[mt], bf[nt], acc[mt][nt], 0, 0, 0);
    }
    __syncthreads();
  }

  #pragma unroll
  for (int mt = 0; mt < 4; mt++) {
    #pragma unroll
    for (int nt = 0; nt < 4; nt++) {
      #pragma unroll
      for (int r = 0; r < 4; r++) {
        int m = m0 + mq * 64 + mt * 16 + (lane >> 4) * 4 + r;
        int n = n0 + nq * 64 + nt * 16 + (lane & 15);
        float v = acc[mt][nt][r];
        if (n < Nreal) {
          v = tanhf(v + bias[n]);
          int t = m >> 6, b = m & 63;           // m = t*64 + b
          ((float*)out)[((size_t)(b * T_ + t)) * F_ + n] = v;
        }
      }
    }
  }
}

// ---------------------------------------------------------------------------
// Pipelined h-load engine (ROUND 9: no sc1 -> L2-cacheable; XCD L2 MSHRs
// merge the 16 synchronized same-line requesters per XCD). Frag (mt,ks)
// lives at lane-base + ks*2048 + mt*256 elements (contiguous 16B).
__device__ __forceinline__ void issue8(const ushort_t* lb, int ks0, u32x4* f) {
  #pragma unroll
  for (int j = 0; j < 8; j++) {
    int mt = j & 3, ks = ks0 + (j >> 2);
    asm volatile("global_load_dwordx4 %0, %1, off"
                 : "=&v"(f[j])
                 : "v"(lb + (size_t)ks * 2048 + mt * 256)
                 : "memory");
  }
}
// counted waits; carry group regs as inout so consumers have a true data
// dependency on the wait (no MFMA hoisting past it).
__device__ __forceinline__ void wait8(u32x4* f) {
  asm volatile("s_waitcnt vmcnt(8)"
               : "+v"(f[0]), "+v"(f[1]), "+v"(f[2]), "+v"(f[3]),
                 "+v"(f[4]), "+v"(f[5]), "+v"(f[6]), "+v"(f[7])
               :: "memory");
}
__device__ __forceinline__ void wait0(u32x4* f) {
  asm volatile("s_waitcnt vmcnt(0)"
               : "+v"(f[0]), "+v"(f[1]), "+v"(f[2]), "+v"(f[3]),
                 "+v"(f[4]), "+v"(f[5]), "+v"(f[6]), "+v"(f[7])
               :: "memory");
}
__device__ __forceinline__ void mfma8(const u32x4* f, int ks0,
    const short8 (&bfr)[4][8], f32x4 (&acc)[4][4]) {
  #pragma unroll
  for (int j = 0; j < 8; j++) {
    int mt = j & 3, ks = ks0 + (j >> 2);
    union { u32x4 u; short8 s; } a; a.u = f[j];
    #pragma unroll
    for (int nt = 0; nt < 4; nt++)
      acc[mt][nt] = __builtin_amdgcn_mfma_f32_16x16x32_bf16(
          a.s, bfr[nt][ks], acc[mt][nt], 0, 0, 0);
  }
}

// One 64x16-output matmul per wave: A rows of packed h tile at `base`
// (= seq + t*65536 elements), K-slice kq*256..+255. Depth-2 pipeline:
// issue g0,g1 -> wait(8)/mfma g0 -> issue g2 -> wait(8)/mfma g1 -> ...
__device__ __forceinline__ void mm_pk(
    const ushort_t* base, int kq, int l15, int l4,
    const short8 (&bfr)[4][8], f32x4 (&acc)[4][4])
{
  const ushort_t* lb = base +
      ((size_t)(kq * 16 + (l4 >> 1)) * 64 + l15) * 16 + (l4 & 1) * 8;
  u32x4 f0[8], f1[8], f2[8], f3[8];
  issue8(lb, 0, f0);
  issue8(lb, 2, f1);
  wait8(f0); mfma8(f0, 0, bfr, acc);
  issue8(lb, 4, f2);
  wait8(f1); mfma8(f1, 2, bfr, acc);
  issue8(lb, 6, f3);
  wait8(f2); mfma8(f2, 4, bfr, acc);
  wait0(f3); mfma8(f3, 6, bfr, acc);
}

// ---------------------------------------------------------------------------
// ballot-poll with light backoff: lanes 0..15 watch the 16 producer WGs of
// this wave's K-slice (lanes 16-63 mirror). Flags stay sc1 atomics.
__device__ __forceinline__ void pollge(const int* p, int tgt) {
  int v = __hip_atomic_load(p, __ATOMIC_RELAXED, __HIP_MEMORY_SCOPE_AGENT);
  while (__ballot(v >= tgt) != ~0ull) {
    __builtin_amdgcn_s_sleep(1);
    v = __hip_atomic_load(p, __ATOMIC_RELAXED, __HIP_MEMORY_SCOPE_AGENT);
  }
}

// ---------------------------------------------------------------------------
// Pipelined recurrence: blocks 0..191 real (layer = b/64, wg = b%64),
// blocks 192..255 clock-burners. 4 waves = 4-way K-split.
__global__ __launch_bounds__(256, 1) void rec_pipe_kernel(
    const ushort_t* __restrict__ xp, const ushort_t* __restrict__ w1p,
    const ushort_t* __restrict__ whh, const ushort_t* __restrict__ wih23,
    const float* __restrict__ bias,
    ushort_t* __restrict__ seq1, ushort_t* __restrict__ seq2,
    ushort_t* __restrict__ seq3, int* __restrict__ slots)
{
  __shared__ float PG[4][64][68];      // 4 disjoint K-partial buffers (69.6KB)
  __shared__ float lds_pad[4096];      // +16KB -> 86KB: force 1 WG/CU

  if (blockIdx.x >= 192) {
    // ---- clock burner: register-only MFMA until done-flag ----
    if (threadIdx.x == 0) lds_pad[0] = 0.f;   // keep pad allocated
    __syncthreads();
    short8 a;
    #pragma unroll
    for (int i = 0; i < 8; i++) a[i] = (short)(threadIdx.x + i);
    f32x4 d0 = {}, d1 = {}, d2 = {}, d3 = {};
    const int* done = slots + DONE_SLOT;
    for (;;) {
      #pragma unroll
      for (int i = 0; i < 32; i++) {
        d0 = __builtin_amdgcn_mfma_f32_16x16x32_bf16(a, a, d0, 0, 0, 0);
        d1 = __builtin_amdgcn_mfma_f32_16x16x32_bf16(a, a, d1, 0, 0, 0);
        d2 = __builtin_amdgcn_mfma_f32_16x16x32_bf16(a, a, d2, 0, 0, 0);
        d3 = __builtin_amdgcn_mfma_f32_16x16x32_bf16(a, a, d3, 0, 0, 0);
      }
      asm volatile("" :: "v"(d0[0]), "v"(d1[0]), "v"(d2[0]), "v"(d3[0]));
      if (__hip_atomic_load(done, __ATOMIC_RELAXED, __HIP_MEMORY_SCOPE_AGENT))
        return;
    }
  }

  const int layer = blockIdx.x >> 6;   // 0..2
  const int wg = blockIdx.x & 63;      // 0..63
  const int tid = threadIdx.x;
  const int kq = tid >> 6, lane = tid & 63;
  const int l15 = lane & 15, l4 = lane >> 4;
  const int jWG = wg * 16;

  ushort_t* my_seq   = (layer == 0) ? seq1 : (layer == 1) ? seq2 : seq3;
  const ushort_t* pv_seq = (layer == 1) ? seq1 : seq2;   // used when layer>0

  // persistent W_hh fragments: (nt=gate, ks): n = nt*1024+jWG+l15,
  // k = kq*256 + ks*32 + l4*8.  128 VGPRs.
  short8 bhh[4][8];
  {
    const ushort_t* wl = whh + (size_t)layer * NG_ * H_;
    #pragma unroll
    for (int nt = 0; nt < 4; nt++)
      #pragma unroll
      for (int ks = 0; ks < 8; ks++)
        bhh[nt][ks] = *(const short8*)(
            wl + ((size_t)(nt * H_ + jWG + l15)) * H_ + kq * 256 + ks * 32 + l4 * 8);
  }
  // W_ih fragments. Layer 0: K=256 total -> wave kq covers k = kq*64 + ks*32,
  // ks in 0..1 (slots [*][0..1]). Layers 1,2: full 8 slots, K layout as bhh.
  short8 bih[4][8];
  if (layer == 0) {
    #pragma unroll
    for (int nt = 0; nt < 4; nt++)
      #pragma unroll
      for (int ks = 0; ks < 2; ks++)
        bih[nt][ks] = *(const short8*)(
            w1p + ((size_t)(nt * H_ + jWG + l15)) * 256 + kq * 64 + ks * 32 + l4 * 8);
  } else {
    const ushort_t* wl = wih23 + (size_t)(layer - 1) * NG_ * H_;
    #pragma unroll
    for (int nt = 0; nt < 4; nt++)
      #pragma unroll
      for (int ks = 0; ks < 8; ks++)
        bih[nt][ks] = *(const short8*)(
            wl + ((size_t)(nt * H_ + jWG + l15)) * H_ + kq * 256 + ks * 32 + l4 * 8);
  }

  // elementwise ownership (round-5 remap, kept): thread (kq,lane) owns
  // batch row eb = kq*16+(lane>>2), j-quad ejq = lane&3.
  const int eb  = kq * 16 + (lane >> 2);
  const int ejq = lane & 3;
  float cst[4] = {0.f, 0.f, 0.f, 0.f};

  // bias enters through xv (constant across t) for ALL layers.
  f32x4 xv[4];
  #pragma unroll
  for (int g = 0; g < 4; g++)
    xv[g] = *(const f32x4*)&bias[layer * NG_ + g * H_ + jWG + ejq * 4];

  const int* slot_own  = slots + (layer * 64 + kq * 16 + l15) * 16;
  const int* slot_prev = slots + ((layer - (layer > 0)) * 64 + kq * 16 + l15) * 16;
  int* slot_my = slots + (layer * 64 + wg) * 16;

  for (int t = 0; t < T_; t++) {
    f32x4 acc[4][4] = {};

    // ---- x-phase first: its input is ready at tick start; own-layer flag
    // propagates underneath it (r5/r7 ordering). ----
    if (layer == 0) {
      short8 ax[4][2];
      #pragma unroll
      for (int mt = 0; mt < 4; mt++)
        #pragma unroll
        for (int ks = 0; ks < 2; ks++)
          ax[mt][ks] = *(const short8*)(
              xp + ((size_t)(t * B_ + mt * 16 + l15)) * 256 + kq * 64 + ks * 32 + l4 * 8);
      #pragma unroll
      for (int ks = 0; ks < 2; ks++)
        #pragma unroll
        for (int mt = 0; mt < 4; mt++)
          #pragma unroll
          for (int nt = 0; nt < 4; nt++)
            acc[mt][nt] = __builtin_amdgcn_mfma_f32_16x16x32_bf16(
                ax[mt][ks], bih[nt][ks], acc[mt][nt], 0, 0, 0);
    } else {
      pollge(slot_prev, t + 1);          // prev layer finished step t
      __builtin_amdgcn_sched_barrier(0);
      mm_pk(pv_seq + (size_t)t * 65536, kq, l15, l4, bih, acc);
    }

    // ---- h-phase ----
    if (t > 0) {
      pollge(slot_own, t);               // own layer finished step t-1
      __builtin_amdgcn_sched_barrier(0);
      mm_pk(my_seq + (size_t)(t - 1) * 65536, kq, l15, l4, bhh, acc);
    }

    // ---- K-partial reduction: 4 disjoint LDS buffers, no atomics ----
    #pragma unroll
    for (int mt = 0; mt < 4; mt++)
      #pragma unroll
      for (int nt = 0; nt < 4; nt++)
        #pragma unroll
        for (int r = 0; r < 4; r++)
          PG[kq][mt * 16 + l4 * 4 + r][nt * 16 + l15] = acc[mt][nt][r];
    __syncthreads();

    // elementwise LSTM cell: thread owns (eb, j = jWG + ejq*4 + u)
    f32x4 p[4];
    #pragma unroll
    for (int g = 0; g < 4; g++) {
      f32x4 p0 = *(const f32x4*)&PG[0][eb][g * 16 + ejq * 4];
      f32x4 p1 = *(const f32x4*)&PG[1][eb][g * 16 + ejq * 4];
      f32x4 p2 = *(const f32x4*)&PG[2][eb][g * 16 + ejq * 4];
      f32x4 p3 = *(const f32x4*)&PG[3][eb][g * 16 + ejq * 4];
      p[g] = (p0 + p1) + (p2 + p3) + xv[g];
    }
    short4v hb;
    #pragma unroll
    for (int u = 0; u < 4; u++) {
      float ii = fsig(p[0][u]);
      float ff = fsig(p[1][u]);
      float gg = ftanh(p[2][u]);
      float oo = fsig(p[3][u]);
      cst[u] = ff * cst[u] + ii * gg;
      hb[u] = (short)f2bf(oo * ftanh(cst[u]));
    }
    union { short4v s; ull u; } hh; hh.s = hb;
    // PACKED store: seq[t][wg][eb][ejq*4..+3]; per wave one contiguous 512B
    // block (tile + kq*512 + lane*8) -> full-line writes, sc1 (bypass L2).
    __hip_atomic_store(
        (ull*)(my_seq + (size_t)t * 65536 + (size_t)wg * 1024
               + (size_t)eb * 16 + ejq * 4),
        hh.u, __ATOMIC_RELAXED, __HIP_MEMORY_SCOPE_AGENT);

    // publish: drain own stores, WG-join (doubles as PG read-complete
    // barrier), then one flag store per WG.
    __builtin_amdgcn_s_waitcnt(0);
    __syncthreads();
    if (tid == 0)
      __hip_atomic_store(slot_my, t + 1,
                         __ATOMIC_RELAXED, __HIP_MEMORY_SCOPE_AGENT);
  }

  // layer-2 WGs release the burners
  if (layer == 2 && tid == 0)
    __hip_atomic_store(slots + DONE_SLOT, 1,
                       __ATOMIC_RELAXED, __HIP_MEMORY_SCOPE_AGENT);
}

// ---------------------------------------------------------------------------
extern "C" void kernel_launch(void* const* d_in, const int* in_sizes, int n_in,
                              void* d_out, int out_size, void* d_ws, size_t ws_size,
                              hipStream_t stream)
{
  (void)in_sizes; (void)n_in; (void)out_size; (void)ws_size;
  const float* X    = (const float*)d_in[0];
  const float* wih1 = (const float*)d_in[1];
  const float* whh1 = (const float*)d_in[2];
  const float* bih1 = (const float*)d_in[3];
  const float* bhh1 = (const float*)d_in[4];
  const float* wih2 = (const float*)d_in[5];
  const float* whh2 = (const float*)d_in[6];
  const float* bih2 = (const float*)d_in[7];
  const float* bhh2 = (const float*)d_in[8];
  const float* wih3 = (const float*)d_in[9];
  const float* whh3 = (const float*)d_in[10];
  const float* bih3 = (const float*)d_in[11];
  const float* bhh3 = (const float*)d_in[12];
  const float* wout = (const float*)d_in[13];
  const float* bout = (const float*)d_in[14];

  const size_t NW = (size_t)NG_ * H_;           // 4M elems
  const size_t sz_seq  = (size_t)MR_ * H_ * 2;  // bf16 h sequence, per layer
  const size_t sz_whh  = 3 * NW * 2;
  const size_t sz_wih  = 2 * NW * 2;
  const size_t sz_w1p  = (size_t)NG_ * 256 * 2;
  const size_t sz_xp   = (size_t)MR_ * 256 * 2;
  const size_t sz_wout = (size_t)F_ * H_ * 2;
  const size_t sz_bias = 3 * (size_t)NG_ * 4;
  const size_t sz_slot = NSLOTI * 4;

  char* ws = (char*)d_ws;
  size_t off = 0;
  auto alloc = [&](size_t bytes) -> void* {
    void* p = ws + off; off += (bytes + 255) & ~(size_t)255; return p;
  };
  ushort_t* seq1    = (ushort_t*)alloc(sz_seq);
  ushort_t* seq2    = (ushort_t*)alloc(sz_seq);
  ushort_t* seq3    = (ushort_t*)alloc(sz_seq);
  ushort_t* whh_bf  = (ushort_t*)alloc(sz_whh);
  ushort_t* wih_bf  = (ushort_t*)alloc(sz_wih);
  ushort_t* w1p     = (ushort_t*)alloc(sz_w1p);
  ushort_t* xp      = (ushort_t*)alloc(sz_xp);
  ushort_t* wout_bf = (ushort_t*)alloc(sz_wout);
  float*    bias    = (float*)alloc(sz_bias);
  int*      slots   = (int*)alloc(sz_slot);
  // total ~146 MB

  init_sync_kernel<<<1, 256, 0, stream>>>(slots);
  prep_kernel<<<1024, 256, 0, stream>>>(
      X, wih1, whh1, bih1, bhh1, wih2, whh2, bih2, bhh2,
      wih3, whh3, bih3, bhh3, wout,
      whh_bf, wih_bf, w1p, xp, wout_bf, bias);

  rec_pipe_kernel<<<256, 256, 0, stream>>>(
      xp, w1p, whh_bf, wih_bf, bias, seq1, seq2, seq3, slots);

  gemm_kernel<<<dim3(128, 1), dim3(256), 0, stream>>>(
      seq3, wout_bf, bout, d_out, 1024, F_);
}

// Round 10
// 1613.206 us; speedup vs baseline: 1.0119x; 1.0009x over previous
//
#include <hip/hip_runtime.h>
#include <stdint.h>
#include <stddef.h>

// ---------------------------------------------------------------------------
// 3-layer LSTM (B=64,T=256,F=64,H=1024) + tanh projection, bf16 MFMA + fp32 acc.
//
// Pipelined: ONE persistent kernel, 192 WGs (64/layer), 258-tick chain.
// Round-10 change (single variable vs r9): NO burner WGs.
//   r7-r9 plateau at 6.1us/tick while the cycle model says ~4.2us at 2.4GHz
//   -- a uniform ~1.4x multiplier = clock below assumption. The 64 burner
//   CUs run continuous dense MFMA (max-current workload); the power manager
//   likely responds by capping frequency chip-wide. Burners were introduced
//   in r4 bundled with the packed-h RMW fix (the likely real winner) and
//   never isolated. This round: grid 192, burner branch removed, everything
//   else identical. If tick worsens, burners were boosting -> revert.
// ---------------------------------------------------------------------------

#define B_ 64
#define T_ 256
#define F_ 64
#define H_ 1024
#define NG_ 4096          // 4*H
#define MR_ (B_*T_)       // 16384 rows, row index = t*64 + b

typedef __attribute__((ext_vector_type(8))) short short8;
typedef __attribute__((ext_vector_type(4))) short short4v;
typedef __attribute__((ext_vector_type(4))) float f32x4;
typedef __attribute__((ext_vector_type(4))) unsigned int u32x4;
typedef unsigned short ushort_t;
typedef unsigned long long ull;

__device__ __forceinline__ float bf2f(ushort_t u) {
  union { float f; unsigned int i; } v; v.i = ((unsigned int)u) << 16; return v.f;
}
__device__ __forceinline__ ushort_t f2bf(float f) {
  union { float f; unsigned int i; } v; v.f = f;
  unsigned int i = v.i;
  unsigned int r = (i + 0x7fffu + ((i >> 16) & 1u)) >> 16;  // RNE
  return (ushort_t)r;
}

__device__ __forceinline__ void gload_lds16(const void* g, void* l) {
  __builtin_amdgcn_global_load_lds(
      (const __attribute__((address_space(1))) void*)g,
      (__attribute__((address_space(3))) void*)l, 16, 0, 0);
}

__device__ __forceinline__ float fsig(float x)  { return 1.f / (1.f + __expf(-x)); }
__device__ __forceinline__ float ftanh(float x) { return 1.f - 2.f / (1.f + __expf(2.f * x)); }

// ---------------------------------------------------------------------------
#define NFLAG 192                 // per-WG flags: 3 layers x 64 WGs
#define NSLOTI ((NFLAG + 1) * 16) // 16-int (64B) stride
__global__ void init_sync_kernel(int* p) {
  for (int i = threadIdx.x; i < NSLOTI; i += blockDim.x)
    __hip_atomic_store(&p[i], 0, __ATOMIC_RELAXED, __HIP_MEMORY_SCOPE_AGENT);
}

// ---------------------------------------------------------------------------
// prep: bf16 casts, hi/lo packing for layer-1 (X ~ N(0,1) needs >bf16), biases.
__global__ void prep_kernel(
    const float* __restrict__ X,
    const float* __restrict__ wih1, const float* __restrict__ whh1,
    const float* __restrict__ bih1, const float* __restrict__ bhh1,
    const float* __restrict__ wih2, const float* __restrict__ whh2,
    const float* __restrict__ bih2, const float* __restrict__ bhh2,
    const float* __restrict__ wih3, const float* __restrict__ whh3,
    const float* __restrict__ bih3, const float* __restrict__ bhh3,
    const float* __restrict__ wout,
    ushort_t* __restrict__ whh_bf, ushort_t* __restrict__ wih_bf,
    ushort_t* __restrict__ w1p, ushort_t* __restrict__ xp,
    ushort_t* __restrict__ wout_bf, float* __restrict__ bias)
{
  long long i0 = (long long)blockIdx.x * blockDim.x + threadIdx.x;
  long long stride = (long long)gridDim.x * blockDim.x;
  const long long NW = (long long)NG_ * H_;  // 4M

  for (long long i = i0; i < NW; i += stride) whh_bf[i]        = f2bf(whh1[i]);
  for (long long i = i0; i < NW; i += stride) whh_bf[NW + i]   = f2bf(whh2[i]);
  for (long long i = i0; i < NW; i += stride) whh_bf[2*NW + i] = f2bf(whh3[i]);
  for (long long i = i0; i < NW; i += stride) wih_bf[i]        = f2bf(wih2[i]);
  for (long long i = i0; i < NW; i += stride) wih_bf[NW + i]   = f2bf(wih3[i]);

  // W1 pack: row n of [4096][256] = [w_hi | w_hi | w_lo | w_lo]
  for (long long i = i0; i < (long long)NG_ * F_; i += stride) {
    int n = (int)(i / F_), f = (int)(i % F_);
    float wv = wih1[i];
    ushort_t hi = f2bf(wv);
    ushort_t lo = f2bf(wv - bf2f(hi));
    ushort_t* row = w1p + (long long)n * 256;
    row[f] = hi; row[64 + f] = hi; row[128 + f] = lo; row[192 + f] = lo;
  }
  // X pack: row (t*64+b) of [16384][256] = [x_hi | x_lo | x_hi | x_lo]
  for (long long i = i0; i < (long long)MR_ * F_; i += stride) {
    int b = (int)(i / (T_ * F_));
    int rem = (int)(i % (T_ * F_));
    int t = rem / F_, f = rem % F_;
    float xv = X[i];
    ushort_t hi = f2bf(xv);
    ushort_t lo = f2bf(xv - bf2f(hi));
    ushort_t* row = xp + ((long long)(t * B_ + b)) * 256;
    row[f] = hi; row[64 + f] = lo; row[128 + f] = hi; row[192 + f] = lo;
  }
  for (long long i = i0; i < (long long)F_ * H_; i += stride) wout_bf[i] = f2bf(wout[i]);
  for (long long i = i0; i < NG_; i += stride) {
    bias[i]          = bih1[i] + bhh1[i];
    bias[NG_ + i]    = bih2[i] + bhh2[i];
    bias[2*NG_ + i]  = bih3[i] + bhh3[i];
  }
}

// ---------------------------------------------------------------------------
// Packed-seq element offset for (row m in [0,16384), k in [0,1024)):
// seq[t = m>>6][wg = k>>4][b = m&63][jl = k&15]
__device__ __forceinline__ size_t pk_off(int row, int k) {
  return ((size_t)((row >> 6) * 64 + (k >> 4)) * 64 + (row & 63)) * 16 + (k & 15);
}

// ---------------------------------------------------------------------------
// GEMM (final projection): C[M=16384, n<64] = A[M,K=1024] * B[n,K]^T, tanh
// epilogue, scatter to [b][t][f] fp32. A is in PACKED seq layout.
__global__ __launch_bounds__(256) void gemm_kernel(
    const ushort_t* __restrict__ A, const ushort_t* __restrict__ Bm,
    const float* __restrict__ bias, void* __restrict__ out,
    int K, int Nreal)
{
  __shared__ ushort_t As[128 * 64];
  __shared__ ushort_t Bs[128 * 64];
  const int tid = threadIdx.x;
  const int w = tid >> 6, lane = tid & 63;
  const int mq = w & 1, nq = w >> 1;
  const int m0 = blockIdx.x * 128, n0 = blockIdx.y * 128;
  const int l8 = lane >> 3, l7 = lane & 7;
  const int kp = l7 ^ l8;  // fetch swizzle so LDS[r][p] holds kpart p^(r&7)

  f32x4 acc[4][4] = {};

  for (int k0 = 0; k0 < K; k0 += 64) {
    #pragma unroll
    for (int q = 0; q < 4; q++) {
      int c = w * 4 + q;                   // chunk 0..15, rows c*8..c*8+7
      int rowA = m0 + c * 8 + l8;
      gload_lds16(A + pk_off(rowA, k0 + kp * 8), (char*)As + c * 1024);
      int rowB = n0 + c * 8 + l8;
      if (rowB >= Nreal) rowB = Nreal - 1;
      gload_lds16(Bm + (size_t)rowB * K + k0 + kp * 8, (char*)Bs + c * 1024);
    }
    __syncthreads();
    #pragma unroll
    for (int ks = 0; ks < 2; ks++) {
      short8 af[4], bf[4];
      #pragma unroll
      for (int mt = 0; mt < 4; mt++) {
        int r = mq * 64 + mt * 16 + (lane & 15);
        int pos = (ks * 4 + (lane >> 4)) ^ (r & 7);
        af[mt] = *(const short8*)((const char*)As + r * 128 + pos * 16);
      }
      #pragma unroll
      for (int nt = 0; nt < 4; nt++) {
        int r = nq * 64 + nt * 16 + (lane & 15);
        int pos = (ks * 4 + (lane >> 4)) ^ (r & 7);
        bf[nt] = *(const short8*)((const char*)Bs + r * 128 + pos * 16);
      }
      #pragma unroll
      for (int mt = 0; mt < 4; mt++)
        #pragma unroll
        for (int nt = 0; nt < 4; nt++)
          acc[mt][nt] = __builtin_amdgcn_mfma_f32_16x16x32_bf16(
              af[mt], bf[nt], acc[mt][nt], 0, 0, 0);
    }
    __syncthreads();
  }

  #pragma unroll
  for (int mt = 0; mt < 4; mt++) {
    #pragma unroll
    for (int nt = 0; nt < 4; nt++) {
      #pragma unroll
      for (int r = 0; r < 4; r++) {
        int m = m0 + mq * 64 + mt * 16 + (lane >> 4) * 4 + r;
        int n = n0 + nq * 64 + nt * 16 + (lane & 15);
        float v = acc[mt][nt][r];
        if (n < Nreal) {
          v = tanhf(v + bias[n]);
          int t = m >> 6, b = m & 63;           // m = t*64 + b
          ((float*)out)[((size_t)(b * T_ + t)) * F_ + n] = v;
        }
      }
    }
  }
}

// ---------------------------------------------------------------------------
// Pipelined h-load engine (r9: plain loads, L2-cacheable; r7 asm pipeline).
// Frag (mt,ks) lives at lane-base + ks*2048 + mt*256 elements (contig 16B).
__device__ __forceinline__ void issue8(const ushort_t* lb, int ks0, u32x4* f) {
  #pragma unroll
  for (int j = 0; j < 8; j++) {
    int mt = j & 3, ks = ks0 + (j >> 2);
    asm volatile("global_load_dwordx4 %0, %1, off"
                 : "=&v"(f[j])
                 : "v"(lb + (size_t)ks * 2048 + mt * 256)
                 : "memory");
  }
}
// counted waits; carry group regs as inout so consumers have a true data
// dependency on the wait (no MFMA hoisting past it).
__device__ __forceinline__ void wait8(u32x4* f) {
  asm volatile("s_waitcnt vmcnt(8)"
               : "+v"(f[0]), "+v"(f[1]), "+v"(f[2]), "+v"(f[3]),
                 "+v"(f[4]), "+v"(f[5]), "+v"(f[6]), "+v"(f[7])
               :: "memory");
}
__device__ __forceinline__ void wait0(u32x4* f) {
  asm volatile("s_waitcnt vmcnt(0)"
               : "+v"(f[0]), "+v"(f[1]), "+v"(f[2]), "+v"(f[3]),
                 "+v"(f[4]), "+v"(f[5]), "+v"(f[6]), "+v"(f[7])
               :: "memory");
}
__device__ __forceinline__ void mfma8(const u32x4* f, int ks0,
    const short8 (&bfr)[4][8], f32x4 (&acc)[4][4]) {
  #pragma unroll
  for (int j = 0; j < 8; j++) {
    int mt = j & 3, ks = ks0 + (j >> 2);
    union { u32x4 u; short8 s; } a; a.u = f[j];
    #pragma unroll
    for (int nt = 0; nt < 4; nt++)
      acc[mt][nt] = __builtin_amdgcn_mfma_f32_16x16x32_bf16(
          a.s, bfr[nt][ks], acc[mt][nt], 0, 0, 0);
  }
}

// One 64x16-output matmul per wave: A rows of packed h tile at `base`
// (= seq + t*65536 elements), K-slice kq*256..+255. Depth-2 pipeline.
__device__ __forceinline__ void mm_pk(
    const ushort_t* base, int kq, int l15, int l4,
    const short8 (&bfr)[4][8], f32x4 (&acc)[4][4])
{
  const ushort_t* lb = base +
      ((size_t)(kq * 16 + (l4 >> 1)) * 64 + l15) * 16 + (l4 & 1) * 8;
  u32x4 f0[8], f1[8], f2[8], f3[8];
  issue8(lb, 0, f0);
  issue8(lb, 2, f1);
  wait8(f0); mfma8(f0, 0, bfr, acc);
  issue8(lb, 4, f2);
  wait8(f1); mfma8(f1, 2, bfr, acc);
  issue8(lb, 6, f3);
  wait8(f2); mfma8(f2, 4, bfr, acc);
  wait0(f3); mfma8(f3, 6, bfr, acc);
}

// ---------------------------------------------------------------------------
// ballot-poll with light backoff: lanes 0..15 watch the 16 producer WGs of
// this wave's K-slice (lanes 16-63 mirror). Flags stay sc1 atomics.
__device__ __forceinline__ void pollge(const int* p, int tgt) {
  int v = __hip_atomic_load(p, __ATOMIC_RELAXED, __HIP_MEMORY_SCOPE_AGENT);
  while (__ballot(v >= tgt) != ~0ull) {
    __builtin_amdgcn_s_sleep(1);
    v = __hip_atomic_load(p, __ATOMIC_RELAXED, __HIP_MEMORY_SCOPE_AGENT);
  }
}

// ---------------------------------------------------------------------------
// Pipelined recurrence: 192 WGs (layer = b/64, wg = b%64). 4 waves = 4-way
// K-split. NO burners this round (clock-throttle probe).
__global__ __launch_bounds__(256, 1) void rec_pipe_kernel(
    const ushort_t* __restrict__ xp, const ushort_t* __restrict__ w1p,
    const ushort_t* __restrict__ whh, const ushort_t* __restrict__ wih23,
    const float* __restrict__ bias,
    ushort_t* __restrict__ seq1, ushort_t* __restrict__ seq2,
    ushort_t* __restrict__ seq3, int* __restrict__ slots)
{
  __shared__ float PG[4][64][68];      // 4 disjoint K-partial buffers (69.6KB)
  __shared__ float lds_pad[4096];      // +16KB -> 86KB: force 1 WG/CU

  const int layer = blockIdx.x >> 6;   // 0..2
  const int wg = blockIdx.x & 63;      // 0..63
  const int tid = threadIdx.x;
  const int kq = tid >> 6, lane = tid & 63;
  const int l15 = lane & 15, l4 = lane >> 4;
  const int jWG = wg * 16;
  if (tid == 0) lds_pad[0] = 0.f;      // keep pad allocated

  ushort_t* my_seq   = (layer == 0) ? seq1 : (layer == 1) ? seq2 : seq3;
  const ushort_t* pv_seq = (layer == 1) ? seq1 : seq2;   // used when layer>0

  // persistent W_hh fragments: (nt=gate, ks): n = nt*1024+jWG+l15,
  // k = kq*256 + ks*32 + l4*8.  128 VGPRs.
  short8 bhh[4][8];
  {
    const ushort_t* wl = whh + (size_t)layer * NG_ * H_;
    #pragma unroll
    for (int nt = 0; nt < 4; nt++)
      #pragma unroll
      for (int ks = 0; ks < 8; ks++)
        bhh[nt][ks] = *(const short8*)(
            wl + ((size_t)(nt * H_ + jWG + l15)) * H_ + kq * 256 + ks * 32 + l4 * 8);
  }
  // W_ih fragments. Layer 0: K=256 total -> wave kq covers k = kq*64 + ks*32,
  // ks in 0..1 (slots [*][0..1]). Layers 1,2: full 8 slots, K layout as bhh.
  short8 bih[4][8];
  if (layer == 0) {
    #pragma unroll
    for (int nt = 0; nt < 4; nt++)
      #pragma unroll
      for (int ks = 0; ks < 2; ks++)
        bih[nt][ks] = *(const short8*)(
            w1p + ((size_t)(nt * H_ + jWG + l15)) * 256 + kq * 64 + ks * 32 + l4 * 8);
  } else {
    const ushort_t* wl = wih23 + (size_t)(layer - 1) * NG_ * H_;
    #pragma unroll
    for (int nt = 0; nt < 4; nt++)
      #pragma unroll
      for (int ks = 0; ks < 8; ks++)
        bih[nt][ks] = *(const short8*)(
            wl + ((size_t)(nt * H_ + jWG + l15)) * H_ + kq * 256 + ks * 32 + l4 * 8);
  }

  // elementwise ownership (round-5 remap, kept): thread (kq,lane) owns
  // batch row eb = kq*16+(lane>>2), j-quad ejq = lane&3.
  const int eb  = kq * 16 + (lane >> 2);
  const int ejq = lane & 3;
  float cst[4] = {0.f, 0.f, 0.f, 0.f};

  // bias enters through xv (constant across t) for ALL layers.
  f32x4 xv[4];
  #pragma unroll
  for (int g = 0; g < 4; g++)
    xv[g] = *(const f32x4*)&bias[layer * NG_ + g * H_ + jWG + ejq * 4];

  const int* slot_own  = slots + (layer * 64 + kq * 16 + l15) * 16;
  const int* slot_prev = slots + ((layer - (layer > 0)) * 64 + kq * 16 + l15) * 16;
  int* slot_my = slots + (layer * 64 + wg) * 16;

  for (int t = 0; t < T_; t++) {
    f32x4 acc[4][4] = {};

    // ---- x-phase first: its input is ready at tick start; own-layer flag
    // propagates underneath it (r5/r7 ordering). ----
    if (layer == 0) {
      short8 ax[4][2];
      #pragma unroll
      for (int mt = 0; mt < 4; mt++)
        #pragma unroll
        for (int ks = 0; ks < 2; ks++)
          ax[mt][ks] = *(const short8*)(
              xp + ((size_t)(t * B_ + mt * 16 + l15)) * 256 + kq * 64 + ks * 32 + l4 * 8);
      #pragma unroll
      for (int ks = 0; ks < 2; ks++)
        #pragma unroll
        for (int mt = 0; mt < 4; mt++)
          #pragma unroll
          for (int nt = 0; nt < 4; nt++)
            acc[mt][nt] = __builtin_amdgcn_mfma_f32_16x16x32_bf16(
                ax[mt][ks], bih[nt][ks], acc[mt][nt], 0, 0, 0);
    } else {
      pollge(slot_prev, t + 1);          // prev layer finished step t
      __builtin_amdgcn_sched_barrier(0);
      mm_pk(pv_seq + (size_t)t * 65536, kq, l15, l4, bih, acc);
    }

    // ---- h-phase ----
    if (t > 0) {
      pollge(slot_own, t);               // own layer finished step t-1
      __builtin_amdgcn_sched_barrier(0);
      mm_pk(my_seq + (size_t)(t - 1) * 65536, kq, l15, l4, bhh, acc);
    }

    // ---- K-partial reduction: 4 disjoint LDS buffers, no atomics ----
    #pragma unroll
    for (int mt = 0; mt < 4; mt++)
      #pragma unroll
      for (int nt = 0; nt < 4; nt++)
        #pragma unroll
        for (int r = 0; r < 4; r++)
          PG[kq][mt * 16 + l4 * 4 + r][nt * 16 + l15] = acc[mt][nt][r];
    __syncthreads();

    // elementwise LSTM cell: thread owns (eb, j = jWG + ejq*4 + u)
    f32x4 p[4];
    #pragma unroll
    for (int g = 0; g < 4; g++) {
      f32x4 p0 = *(const f32x4*)&PG[0][eb][g * 16 + ejq * 4];
      f32x4 p1 = *(const f32x4*)&PG[1][eb][g * 16 + ejq * 4];
      f32x4 p2 = *(const f32x4*)&PG[2][eb][g * 16 + ejq * 4];
      f32x4 p3 = *(const f32x4*)&PG[3][eb][g * 16 + ejq * 4];
      p[g] = (p0 + p1) + (p2 + p3) + xv[g];
    }
    short4v hb;
    #pragma unroll
    for (int u = 0; u < 4; u++) {
      float ii = fsig(p[0][u]);
      float ff = fsig(p[1][u]);
      float gg = ftanh(p[2][u]);
      float oo = fsig(p[3][u]);
      cst[u] = ff * cst[u] + ii * gg;
      hb[u] = (short)f2bf(oo * ftanh(cst[u]));
    }
    union { short4v s; ull u; } hh; hh.s = hb;
    // PACKED store: seq[t][wg][eb][ejq*4..+3]; per wave one contiguous 512B
    // block (tile + kq*512 + lane*8) -> full-line writes, sc1 (bypass L2).
    __hip_atomic_store(
        (ull*)(my_seq + (size_t)t * 65536 + (size_t)wg * 1024
               + (size_t)eb * 16 + ejq * 4),
        hh.u, __ATOMIC_RELAXED, __HIP_MEMORY_SCOPE_AGENT);

    // publish: drain own stores, WG-join (doubles as PG read-complete
    // barrier), then one flag store per WG.
    __builtin_amdgcn_s_waitcnt(0);
    __syncthreads();
    if (tid == 0)
      __hip_atomic_store(slot_my, t + 1,
                         __ATOMIC_RELAXED, __HIP_MEMORY_SCOPE_AGENT);
  }
}

// ---------------------------------------------------------------------------
extern "C" void kernel_launch(void* const* d_in, const int* in_sizes, int n_in,
                              void* d_out, int out_size, void* d_ws, size_t ws_size,
                              hipStream_t stream)
{
  (void)in_sizes; (void)n_in; (void)out_size; (void)ws_size;
  const float* X    = (const float*)d_in[0];
  const float* wih1 = (const float*)d_in[1];
  const float* whh1 = (const float*)d_in[2];
  const float* bih1 = (const float*)d_in[3];
  const float* bhh1 = (const float*)d_in[4];
  const float* wih2 = (const float*)d_in[5];
  const float* whh2 = (const float*)d_in[6];
  const float* bih2 = (const float*)d_in[7];
  const float* bhh2 = (const float*)d_in[8];
  const float* wih3 = (const float*)d_in[9];
  const float* whh3 = (const float*)d_in[10];
  const float* bih3 = (const float*)d_in[11];
  const float* bhh3 = (const float*)d_in[12];
  const float* wout = (const float*)d_in[13];
  const float* bout = (const float*)d_in[14];

  const size_t NW = (size_t)NG_ * H_;           // 4M elems
  const size_t sz_seq  = (size_t)MR_ * H_ * 2;  // bf16 h sequence, per layer
  const size_t sz_whh  = 3 * NW * 2;
  const size_t sz_wih  = 2 * NW * 2;
  const size_t sz_w1p  = (size_t)NG_ * 256 * 2;
  const size_t sz_xp   = (size_t)MR_ * 256 * 2;
  const size_t sz_wout = (size_t)F_ * H_ * 2;
  const size_t sz_bias = 3 * (size_t)NG_ * 4;
  const size_t sz_slot = NSLOTI * 4;

  char* ws = (char*)d_ws;
  size_t off = 0;
  auto alloc = [&](size_t bytes) -> void* {
    void* p = ws + off; off += (bytes + 255) & ~(size_t)255; return p;
  };
  ushort_t* seq1    = (ushort_t*)alloc(sz_seq);
  ushort_t* seq2    = (ushort_t*)alloc(sz_seq);
  ushort_t* seq3    = (ushort_t*)alloc(sz_seq);
  ushort_t* whh_bf  = (ushort_t*)alloc(sz_whh);
  ushort_t* wih_bf  = (ushort_t*)alloc(sz_wih);
  ushort_t* w1p     = (ushort_t*)alloc(sz_w1p);
  ushort_t* xp      = (ushort_t*)alloc(sz_xp);
  ushort_t* wout_bf = (ushort_t*)alloc(sz_wout);
  float*    bias    = (float*)alloc(sz_bias);
  int*      slots   = (int*)alloc(sz_slot);
  // total ~146 MB

  init_sync_kernel<<<1, 256, 0, stream>>>(slots);
  prep_kernel<<<1024, 256, 0, stream>>>(
      X, wih1, whh1, bih1, bhh1, wih2, whh2, bih2, bhh2,
      wih3, whh3, bih3, bhh3, wout,
      whh_bf, wih_bf, w1p, xp, wout_bf, bias);

  rec_pipe_kernel<<<192, 256, 0, stream>>>(
      xp, w1p, whh_bf, wih_bf, bias, seq1, seq2, seq3, slots);

  gemm_kernel<<<dim3(128, 1), dim3(256), 0, stream>>>(
      seq3, wout_bf, bout, d_out, 1024, F_);
}